// Round 6
// baseline (410.377 us; speedup 1.0000x reference)
//
#include <hip/hip_runtime.h>

// Relational GCN fwd: hidden = tanh((Σe inv_deg⊙adj_e)@h0 + h0); out = tanh(A@(hidden@W2+b2) + o0)
// A built once (bf16); layer GEMMs use mfma_f32_16x16x32_bf16; self-loops stay f32.
// K2 stages adj rows via global_load_lds (DMA queue => ~160KB in flight/CU, HBM-saturating).
#define BATCH 64
#define NE    4
#define NN    512

typedef __attribute__((ext_vector_type(4))) float f32x4;
typedef __attribute__((ext_vector_type(8))) short s16x8;
typedef __attribute__((ext_vector_type(8))) unsigned short u16x8;

__device__ __forceinline__ unsigned short f2bf(float f) {
  unsigned u = __builtin_bit_cast(unsigned, f);
  u += 0x7fffu + ((u >> 16) & 1u);     // RNE (inputs are finite)
  return (unsigned short)(u >> 16);
}

// ---------------- K1: h0 = x@W1 + b1 -> h0 f32 [B][512][64], h0T bf16 [B][64][512]
__global__ __launch_bounds__(256) void k_h0(const float* __restrict__ x,
                                            const float* __restrict__ W1,
                                            const float* __restrict__ b1,
                                            float* __restrict__ h0,
                                            unsigned short* __restrict__ h0T) {
  __shared__ float W1s[64][68];
  __shared__ float xs[64][68];
  __shared__ float Ts[64][68];
  int t = threadIdx.x;
  int b = blockIdx.x >> 3;
  int mt = (blockIdx.x & 7) * 64;
  #pragma unroll
  for (int i = 0; i < 4; ++i) {                 // W1: 1024 float4
    int idx = i * 256 + t;
    int k = idx >> 4, cq = idx & 15;
    *reinterpret_cast<float4*>(&W1s[k][cq * 4]) = reinterpret_cast<const float4*>(W1)[idx];
  }
  const float* xb = x + ((size_t)b * NN + mt) * 64;
  #pragma unroll
  for (int i = 0; i < 4; ++i) {                 // x tile: 1024 float4
    int idx = i * 256 + t;
    int m = idx >> 4, cq = idx & 15;
    *reinterpret_cast<float4*>(&xs[m][cq * 4]) = reinterpret_cast<const float4*>(xb)[idx];
  }
  __syncthreads();
  int c = t & 63, rg = t >> 6;
  float acc[16];
  float bias = b1[c];
  #pragma unroll
  for (int i = 0; i < 16; ++i) acc[i] = bias;
  for (int k = 0; k < 64; ++k) {
    float w = W1s[k][c];
    #pragma unroll
    for (int i = 0; i < 16; ++i) acc[i] += xs[rg * 16 + i][k] * w;
  }
  float* h0b = h0 + ((size_t)b * NN + mt) * 64;
  #pragma unroll
  for (int i = 0; i < 16; ++i) {
    h0b[(size_t)(rg * 16 + i) * 64 + c] = acc[i];
    Ts[c][rg * 16 + i] = acc[i];                // transpose via LDS
  }
  __syncthreads();
  int d = t >> 2, mq = t & 3;
  unsigned short* dst = h0T + ((size_t)b * 64 + d) * NN + mt + mq * 16;
  u16x8 oa, ob;
  #pragma unroll
  for (int j = 0; j < 8; ++j) oa[j] = f2bf(Ts[d][mq * 16 + j]);
  #pragma unroll
  for (int j = 0; j < 8; ++j) ob[j] = f2bf(Ts[d][mq * 16 + 8 + j]);
  *reinterpret_cast<u16x8*>(dst) = oa;
  *reinterpret_cast<u16x8*>(dst + 8) = ob;
}

// ---------------- K2: A[b] = Σe inv_deg ⊙ adj[b,e]  (bf16 out)
// One wave per row. Rows staged to wave-private LDS slices via global_load_lds
// (width 16): 8 issues/wave, no VGPR held => DMA queue saturates HBM.
__global__ __launch_bounds__(256) void k_build_A(const float* __restrict__ adj,
                                                 unsigned short* __restrict__ A) {
  __shared__ float lds[4][NE][NN];              // [wave][edge][col] = 32 KB
  int t = threadIdx.x;
  int lane = t & 63;
  int w = t >> 6;
  int idx = blockIdx.x * 4 + w;                 // [0, B*N)
  const size_t estride = (size_t)NN * NN;
  const float* base = adj + (size_t)(idx >> 9) * NE * estride + (size_t)(idx & 511) * NN;
  #pragma unroll
  for (int e = 0; e < NE; ++e) {
    #pragma unroll
    for (int h = 0; h < 2; ++h) {               // 2 x 1KB chunks per edge-row
      __builtin_amdgcn_global_load_lds(
          (const __attribute__((address_space(1))) void*)(base + (size_t)e * estride + h * 256 + lane * 4),
          (__attribute__((address_space(3))) void*)&lds[w][e][h * 256],
          16, 0, 0);
    }
  }
  asm volatile("s_waitcnt vmcnt(0)" ::: "memory");   // wave-private slices: no barrier
  float po[8] = {0, 0, 0, 0, 0, 0, 0, 0};
  #pragma unroll
  for (int e = 0; e < NE; ++e) {
    float4 v0 = *reinterpret_cast<const float4*>(&lds[w][e][lane * 8]);
    float4 v1 = *reinterpret_cast<const float4*>(&lds[w][e][lane * 8 + 4]);
    float s = v0.x + v0.y + v0.z + v0.w + v1.x + v1.y + v1.z + v1.w;
    #pragma unroll
    for (int off = 32; off; off >>= 1) s += __shfl_xor(s, off);
    float inv = 1.0f / (s + 1.0f);
    po[0] += inv * v0.x; po[1] += inv * v0.y; po[2] += inv * v0.z; po[3] += inv * v0.w;
    po[4] += inv * v1.x; po[5] += inv * v1.y; po[6] += inv * v1.z; po[7] += inv * v1.w;
  }
  u16x8 ob;
  #pragma unroll
  for (int j = 0; j < 8; ++j) ob[j] = f2bf(po[j]);
  *reinterpret_cast<u16x8*>(A + (size_t)idx * NN + lane * 8) = ob;
}

// ---------------- K3: o0 = tanh(A@h0 + h0) @ W2 + b2 ; writes o0 f32 + o0T bf16
__global__ __launch_bounds__(256) void k_layer1(const unsigned short* __restrict__ A,
                                                const unsigned short* __restrict__ h0T,
                                                const float* __restrict__ h0,
                                                const float* __restrict__ W2,
                                                const float* __restrict__ b2,
                                                float* __restrict__ o0,
                                                unsigned short* __restrict__ o0T) {
  __shared__ unsigned short LT[64][520];   // h0T tile [d][m], pad->bank-uniform b128
  __shared__ unsigned short Hs[64][72];    // hidden bf16 (144B rows, 16B aligned)
  __shared__ unsigned short W2T[32][72];
  int t = threadIdx.x;
  int b = blockIdx.x >> 3;
  int brow = (blockIdx.x & 7) * 64;
  const u16x8* src = reinterpret_cast<const u16x8*>(h0T + (size_t)b * 64 * NN);
  #pragma unroll
  for (int i = 0; i < 16; ++i) {           // 4096 16B chunks
    int idx = i * 256 + t;
    int d = idx >> 6, ch = idx & 63;
    *reinterpret_cast<u16x8*>(&LT[d][ch * 8]) = src[idx];
  }
  {
    int d0 = t >> 2, d1b = (t & 3) * 8;
    #pragma unroll
    for (int j = 0; j < 8; ++j)
      W2T[d1b + j][d0] = f2bf(W2[(size_t)d0 * 32 + d1b + j]);
  }
  __syncthreads();
  int lane = t & 63, w = t >> 6;
  int cl = lane & 15, g = lane >> 4;
  int wrow = w * 16;
  const unsigned short* Ab = A + ((size_t)b * NN + brow + wrow + cl) * NN;
  f32x4 acc[4] = {};
  for (int ks = 0; ks < 16; ++ks) {
    s16x8 af = *reinterpret_cast<const s16x8*>(Ab + ks * 32 + g * 8);
    #pragma unroll
    for (int n = 0; n < 4; ++n) {
      s16x8 bf = *reinterpret_cast<const s16x8*>(&LT[n * 16 + cl][ks * 32 + g * 8]);
      acc[n] = __builtin_amdgcn_mfma_f32_16x16x32_bf16(af, bf, acc[n], 0, 0, 0);
    }
  }
  // epilogue1: tanh(acc + h0 f32) -> Hs bf16  (C/D map: col=lane&15, row=g*4+reg)
  const float* h0r = h0 + ((size_t)b * NN + brow + wrow) * 64;
  #pragma unroll
  for (int n = 0; n < 4; ++n) {
    #pragma unroll
    for (int q = 0; q < 4; ++q) {
      int row = g * 4 + q;
      float hv = h0r[(size_t)row * 64 + n * 16 + cl];
      Hs[wrow + row][n * 16 + cl] = f2bf(tanhf(acc[n][q] + hv));
    }
  }
  __syncthreads();
  // GEMM2: o0 = Hs @ W2 (K=64)
  f32x4 acc2[2] = {};
  #pragma unroll
  for (int ks = 0; ks < 2; ++ks) {
    s16x8 hf = *reinterpret_cast<const s16x8*>(&Hs[wrow + cl][ks * 32 + g * 8]);
    #pragma unroll
    for (int n = 0; n < 2; ++n) {
      s16x8 wf = *reinterpret_cast<const s16x8*>(&W2T[n * 16 + cl][ks * 32 + g * 8]);
      acc2[n] = __builtin_amdgcn_mfma_f32_16x16x32_bf16(hf, wf, acc2[n], 0, 0, 0);
    }
  }
  float* o0r = o0 + ((size_t)b * NN + brow + wrow) * 32;
  unsigned short* oTb = o0T + (size_t)b * 32 * NN + (brow + wrow);
  #pragma unroll
  for (int n = 0; n < 2; ++n) {
    float bias = b2[n * 16 + cl];
    #pragma unroll
    for (int q = 0; q < 4; ++q) {
      int row = g * 4 + q;
      float val = acc2[n][q] + bias;
      o0r[(size_t)row * 32 + n * 16 + cl] = val;
      oTb[(size_t)(n * 16 + cl) * NN + row] = f2bf(val);   // scattered 2B; L2 merges
    }
  }
}

// ---------------- K4: out = tanh(A@o0 + o0)
__global__ __launch_bounds__(256) void k_layer2(const unsigned short* __restrict__ A,
                                                const unsigned short* __restrict__ o0T,
                                                const float* __restrict__ o0,
                                                float* __restrict__ out) {
  __shared__ unsigned short OT[32][520];
  int t = threadIdx.x;
  int b = blockIdx.x >> 3;
  int brow = (blockIdx.x & 7) * 64;
  const u16x8* src = reinterpret_cast<const u16x8*>(o0T + (size_t)b * 32 * NN);
  #pragma unroll
  for (int i = 0; i < 8; ++i) {            // 2048 16B chunks
    int idx = i * 256 + t;
    int d = idx >> 6, ch = idx & 63;
    *reinterpret_cast<u16x8*>(&OT[d][ch * 8]) = src[idx];
  }
  __syncthreads();
  int lane = t & 63, w = t >> 6;
  int cl = lane & 15, g = lane >> 4;
  int wrow = w * 16;
  const unsigned short* Ab = A + ((size_t)b * NN + brow + wrow + cl) * NN;
  f32x4 acc[2] = {};
  for (int ks = 0; ks < 16; ++ks) {
    s16x8 af = *reinterpret_cast<const s16x8*>(Ab + ks * 32 + g * 8);
    #pragma unroll
    for (int n = 0; n < 2; ++n) {
      s16x8 bf = *reinterpret_cast<const s16x8*>(&OT[n * 16 + cl][ks * 32 + g * 8]);
      acc[n] = __builtin_amdgcn_mfma_f32_16x16x32_bf16(af, bf, acc[n], 0, 0, 0);
    }
  }
  const float* o0r = o0 + ((size_t)b * NN + brow + wrow) * 32;
  float* outr = out + ((size_t)b * NN + brow + wrow) * 32;
  #pragma unroll
  for (int n = 0; n < 2; ++n) {
    #pragma unroll
    for (int q = 0; q < 4; ++q) {
      int row = g * 4 + q;
      float self = o0r[(size_t)row * 32 + n * 16 + cl];
      outr[(size_t)row * 32 + n * 16 + cl] = tanhf(acc[n][q] + self);
    }
  }
}

extern "C" void kernel_launch(void* const* d_in, const int* in_sizes, int n_in,
                              void* d_out, int out_size, void* d_ws, size_t ws_size,
                              hipStream_t stream) {
  const float* x   = (const float*)d_in[0];
  const float* adj = (const float*)d_in[1];
  const float* W1  = (const float*)d_in[2];
  const float* b1  = (const float*)d_in[3];
  const float* W2  = (const float*)d_in[4];
  const float* b2  = (const float*)d_in[5];
  float* out = (float*)d_out;

  char* ws = (char*)d_ws;
  unsigned short* A   = (unsigned short*)ws;                          // 33,554,432 B
  float*          h0  = (float*)(ws + 33554432);                      //  8,388,608 B
  unsigned short* h0T = (unsigned short*)(ws + 33554432 + 8388608);   //  4,194,304 B
  float*          o0  = (float*)(ws + 46137344);                      //  4,194,304 B
  unsigned short* o0T = (unsigned short*)(ws + 50331648);             //  2,097,152 B

  k_h0     <<<BATCH * 8,      256, 0, stream>>>(x, W1, b1, h0, h0T);
  k_build_A<<<BATCH * NN / 4, 256, 0, stream>>>(adj, A);
  k_layer1 <<<BATCH * 8,      256, 0, stream>>>(A, h0T, h0, W2, b2, o0, o0T);
  k_layer2 <<<BATCH * 8,      256, 0, stream>>>(A, o0T, o0, out);
}